// Round 8
// baseline (330.610 us; speedup 1.0000x reference)
//
#include <hip/hip_runtime.h>

typedef __attribute__((ext_vector_type(8))) short bf16x8;
typedef __attribute__((ext_vector_type(4))) float f32x4;
typedef __attribute__((ext_vector_type(2))) unsigned int u32x2;
typedef __attribute__((ext_vector_type(4))) unsigned int u32x4;
typedef __attribute__((ext_vector_type(2))) __bf16 bf16x2t;
typedef unsigned short u16;
typedef unsigned int u32;

#define DI __device__ __forceinline__

// Problem constants: B=8, A=1024, NB=64, NAB=NF=128, NG=25, NI=3

DI float b2f(u16 u){ union{u32 i; float f;} v; v.i = ((u32)u)<<16; return v.f; }
DI u16 f2b(float f){ union{float f; u32 i;} v; v.f=f; u32 u=v.i;
                     return (u16)((u + 0x7fffu + ((u>>16)&1u))>>16); }
// packed 2xf32 -> 2xbf16; lo = low 16 bits.  v_cvt_pk_bf16_f32 when available.
DI u32 pk2(float lo, float hi){
#if __has_builtin(__builtin_amdgcn_cvt_pk_bf16_f32)
  bf16x2t h = __builtin_amdgcn_cvt_pk_bf16_f32(lo, hi);
  u32 d; __builtin_memcpy(&d, &h, 4); return d;
#else
  return (u32)f2b(lo) | ((u32)f2b(hi)<<16);
#endif
}
// native exp2/log2 (single v_exp_f32 / v_log_f32)
DI float fexp2(float x){
#if __has_builtin(__builtin_amdgcn_exp2f)
  return __builtin_amdgcn_exp2f(x);
#else
  return __expf(x*0.6931471805599453f);
#endif
}
DI float flog2(float x){
#if __has_builtin(__builtin_amdgcn_logf)
  return __builtin_amdgcn_logf(x);
#else
  return __logf(x)*1.4426950408889634f;
#endif
}
// dtype-agnostic input load (element index): isbf ? bf16 : f32
DI float ldin(const void* p, size_t i, int isbf){
  return isbf ? b2f(((const u16*)p)[i]) : ((const float*)p)[i];
}
// 4 consecutive elements (i % 4 == 0)
DI f32x4 ldin4(const void* p, size_t i, int isbf){
  if(isbf){
    u32x2 d = *(const u32x2*)((const u16*)p + i);
    f32x4 r;
    r[0] = b2f((u16)(d[0]&0xffff)); r[1] = b2f((u16)(d[0]>>16));
    r[2] = b2f((u16)(d[1]&0xffff)); r[3] = b2f((u16)(d[1]>>16));
    return r;
  }
  return *(const f32x4*)((const float*)p + i);
}
DI int probe_bf(const void* nmask){ return ((const u16*)nmask)[0] == 0x3F80u; }

DI f32x4 mfma16(bf16x8 a, bf16x8 b, f32x4 c){
  return __builtin_amdgcn_mfma_f32_16x16x32_bf16(a,b,c,0,0,0);
}
// fragment (8 consecutive k as bf16) from fp32 global memory
DI bf16x8 ldfragA_f32(const float* p){
  f32x4 a = ((const f32x4*)p)[0], b = ((const f32x4*)p)[1];
  union{ u32 d[4]; bf16x8 v; } u;
  u.d[0]=pk2(a[0],a[1]); u.d[1]=pk2(a[2],a[3]);
  u.d[2]=pk2(b[0],b[1]); u.d[3]=pk2(b[2],b[3]);
  return u.v;
}
DI float sspf(float x){            // ssp = log(1+e^x) - ln2  (|x| << 80 guaranteed)
  return __logf(1.f + __expf(x)) - 0.6931471805599453f;
}

// WF layout per interaction (u16 offsets; frag = 512 u16):
//   fw1   frags 0..7    off 0      (K=32: rows 0..24 = fw1*log2e, 25 = fb1*log2e)
//   fw2   frags 8..47   off 4096   (kk 0..4; kk=4 row k=128 = fb2, rest 0)
//   in2f  frags 48..79  off 24576
//   f2o   frags 80..111 off 40960
//   dense frags 112..143 off 57344
// interaction stride = 73728 u16
#define WF_STRIDE 73728
#define WF_FW2    4096
#define WF_IN2F   24576
#define WF_F2O    40960
#define WF_DEN    57344

// ---------------------------------------------------------------------------
// Fused setup: blocks [0,4096) embed | [4096,6144) dist | [6144,6252) wfrag
__global__ __launch_bounds__(256) void k_setup(const void* __restrict__ pos,
                                               const void* __restrict__ cell,
                                               const void* __restrict__ cello,
                                               const void* __restrict__ nmask,
                                               const void* __restrict__ emb,
                                               const void* __restrict__ fw1,
                                               const void* __restrict__ fb1,
                                               const void* __restrict__ fw2,
                                               const void* __restrict__ fb2,
                                               const void* __restrict__ in2f,
                                               const void* __restrict__ f2o,
                                               const void* __restrict__ den,
                                               const int* __restrict__ z,
                                               const int* __restrict__ nbrs,
                                               float* __restrict__ X,
                                               float* __restrict__ R,
                                               float* __restrict__ CM,
                                               u16* __restrict__ WF){
  int isbf = probe_bf(nmask);
  int bx = blockIdx.x, tid = threadIdx.x;
  if(bx < 4096){
    int idx = bx*256 + tid;                    // < 8192*128
    int a = idx>>7, f = idx&127;
    X[idx] = ldin(emb, (size_t)z[a]*128 + f, isbf);
    return;
  }
  if(bx < 6144){
    int pairIdx = (bx-4096)*256 + tid;         // < 8192*64
    int atom = pairIdx>>6;
    int b = atom>>10;
    int nb = nbrs[pairIdx];
    int jrow = (b<<10) + nb;
    float pi0=ldin(pos,atom*3+0,isbf), pi1=ldin(pos,atom*3+1,isbf), pi2=ldin(pos,atom*3+2,isbf);
    float pj0=ldin(pos,jrow*3+0,isbf), pj1=ldin(pos,jrow*3+1,isbf), pj2=ldin(pos,jrow*3+2,isbf);
    float co0=ldin(cello,(size_t)pairIdx*3+0,isbf),
          co1=ldin(cello,(size_t)pairIdx*3+1,isbf),
          co2=ldin(cello,(size_t)pairIdx*3+2,isbf);
    size_t cb = (size_t)b*9;
    pj0 += co0*ldin(cell,cb+0,isbf) + co1*ldin(cell,cb+3,isbf) + co2*ldin(cell,cb+6,isbf);
    pj1 += co0*ldin(cell,cb+1,isbf) + co1*ldin(cell,cb+4,isbf) + co2*ldin(cell,cb+7,isbf);
    pj2 += co0*ldin(cell,cb+2,isbf) + co1*ldin(cell,cb+5,isbf) + co2*ldin(cell,cb+8,isbf);
    float d0 = pj0-pi0, d1 = pj1-pi1, d2 = pj2-pi2;
    float dd = d0*d0 + d1*d1 + d2*d2;
    float m  = ldin(nmask,pairIdx,isbf);
    float r  = sqrtf(m>0.f ? dd : 1.f) * m;
    R[pairIdx] = r;
    float c = 0.5f*(__cosf(r*3.14159265358979f/5.f)+1.f) * ((r<5.f)?1.f:0.f) * m;
    CM[pairIdx] = c;
    return;
  }
  // weight fragments: wid in [0,432) = 3 interactions x 144 frags
  int wid = (bx-6144)*4 + (tid>>6);
  int lane = tid & 63;
  int q = lane>>4, l15 = lane&15;
  int i = wid/144, r = wid%144;
  int mat, kk, t;
  if(r < 8){ mat=0; kk=0; t=r; }
  else if(r < 48){ int r2 = r-8; mat=1; kk=r2>>3; t=r2&7; }
  else { int r3 = r-48; mat = 2 + (r3>>5); kk = (r3>>3)&3; t = r3&7; }
  const void* src; size_t sbase; int K; int off;
  switch(mat){
    case 0:  src = fw1;  sbase=(size_t)i*3200;  K=25;  off=0;       break;
    case 1:  src = fw2;  sbase=(size_t)i*16384; K=128; off=WF_FW2;  break;
    case 2:  src = in2f; sbase=(size_t)i*16384; K=128; off=WF_IN2F; break;
    case 3:  src = f2o;  sbase=(size_t)i*16384; K=128; off=WF_F2O;  break;
    default: src = den;  sbase=(size_t)i*16384; K=128; off=WF_DEN;  break;
  }
  int c = t*16 + l15;
  bf16x8 frag;
  #pragma unroll
  for(int j=0;j<8;j++){
    int k = kk*32 + q*8 + j;
    float v;
    if(k < K)                 v = ldin(src, sbase + (size_t)k*128 + c, isbf);
    else if(mat==0 && k==25)  v = ldin(fb1, (size_t)i*128 + c, isbf);   // bias row
    else if(mat==1 && k==128) v = ldin(fb2, (size_t)i*128 + c, isbf);   // fb2 row (H bias col = cm)
    else                      v = 0.f;
    if(mat==0) v *= 1.4426950408889634f;       // log2e pre-scale (exp2 domain)
    frag[j] = (short)f2b(v);
  }
  *(bf16x8*)(WF + (size_t)i*WF_STRIDE + off + ((kk*8+t)*64 + lane)*8) = frag;
}

// ---------------------------------------------------------------------------
// y = x @ in2f (iteration 0).  One wave per block -> 512 blocks (full GPU).
__global__ __launch_bounds__(64) void k_proj(const float* __restrict__ X,
                                             const u16* __restrict__ wf,
                                             float* __restrict__ Y){
  int wid = blockIdx.x;                        // tile id < 512
  int lane = threadIdx.x;
  int q = lane>>4, l15 = lane&15;
  int row0 = wid*16;
  f32x4 acc[8];
  #pragma unroll
  for(int t=0;t<8;t++) acc[t] = (f32x4){0.f,0.f,0.f,0.f};
  #pragma unroll
  for(int kk=0;kk<4;kk++){
    bf16x8 xf = ldfragA_f32(X + (size_t)(row0+l15)*128 + kk*32 + q*8);
    #pragma unroll
    for(int t=0;t<8;t++){
      bf16x8 wv = *(const bf16x8*)(wf + ((kk*8+t)*64 + lane)*8);
      acc[t] = mfma16(wv, xf, acc[t]);        // transposed: D[col t*16+q*4+r][row l15]
    }
  }
  #pragma unroll
  for(int t=0;t<8;t++)
    *(f32x4*)(Y + (size_t)(row0+l15)*128 + t*16 + q*4) = acc[t];
}

// ---------------------------------------------------------------------------
// CFConv: one block per atom, wave = neighbor m-tile.
//  - Y gather prefetched into registers before S1 (hides L2 latency).
//  - fb2*cm folded into S2 via H bias column (H[.,128]=cm, fw2 k=128 row=fb2).
//  - fw1 frags read directly from global (L2-hot 4 KB), no LDS staging/barrier.
//  - ssp in exp2/log2 domain (fw1 pre-scaled by log2e).
// NOTE (R4/R5): gfx950 unified VGPR/AGPR file — NO min-waves launch_bounds arg
// (forces arch/acc split -> scratch spills).
__global__ __launch_bounds__(256) void k_cfconv(const float* __restrict__ R,
                                                const float* __restrict__ CM,
                                                const float* __restrict__ Y,
                                                const int* __restrict__ nbrs,
                                                const u16* __restrict__ fw1f,
                                                const u16* __restrict__ fw2f,
                                                float* __restrict__ AGG){
  __shared__ __align__(16) u16 Hb[4][16][168];     // 21 KB per-wave H tiles (160 cols + pad)
  __shared__ float Red[4][128];                    // 2 KB partial aggs
  int tid = threadIdx.x;
  int mt  = tid>>6;                 // wave index == m-tile index
  int lane = tid & 63;
  int q = lane>>4, l15 = lane&15;
  int atom = blockIdx.x;
  int bbase = atom & ~1023;
  u16 (*H)[168] = Hb[mt];

  // --- Y gather prefetch (addresses depend only on nbrs) ---
  int4 nb4 = *(const int4*)(nbrs + (size_t)atom*64 + mt*16 + q*4);
  const float* yp0 = Y + (size_t)(bbase+nb4.x)*128 + l15;
  const float* yp1 = Y + (size_t)(bbase+nb4.y)*128 + l15;
  const float* yp2 = Y + (size_t)(bbase+nb4.z)*128 + l15;
  const float* yp3 = Y + (size_t)(bbase+nb4.w)*128 + l15;
  float yv0[8], yv1[8], yv2[8], yv3[8];
  #pragma unroll
  for(int t=0;t<8;t++){
    yv0[t]=yp0[t*16]; yv1[t]=yp1[t*16]; yv2[t]=yp2[t*16]; yv3[t]=yp3[t*16];
  }

  const float width = 5.0f/24.0f;
  const float c2 = (-0.5f/(width*width))*1.4426950408889634f;  // coeff*log2e
  float r    = R [(size_t)atom*64 + mt*16 + l15];
  float cm_l = CM[(size_t)atom*64 + mt*16 + l15];
  float cmln2 = 0.69314718055994531f*cm_l;

  // gaussian B-frag in exp2 domain (k=25 -> 1.0 bias slot)
  float gv[8];
  #pragma unroll
  for(int j=0;j<8;j++){
    int k = q*8+j;
    if(k < 25){ float t = fmaf(-width,(float)k,r); gv[j] = fexp2(c2*t*t); }
    else gv[j] = (k==25) ? 1.f : 0.f;
  }
  union{ u32 d[4]; bf16x8 v; } afu;
  afu.d[0]=pk2(gv[0],gv[1]); afu.d[1]=pk2(gv[2],gv[3]);
  afu.d[2]=pk2(gv[4],gv[5]); afu.d[3]=pk2(gv[6],gv[7]);
  bf16x8 af = afu.v;

  // S1': acc = (fw1*log2e)^T @ f^T  — fw1 frags straight from global (L2-hot)
  f32x4 acc[8];
  #pragma unroll
  for(int t=0;t<8;t++){
    bf16x8 w1 = *(const bf16x8*)(fw1f + (size_t)t*512 + lane*8);
    acc[t] = mfma16(w1, af, (f32x4){0.f,0.f,0.f,0.f});
  }
  // h = cmln2*(log2(1+2^acc) - 1);  pack pairs; one b64 write per t
  #pragma unroll
  for(int t=0;t<8;t++){
    float h0 = fmaf(flog2(1.f+fexp2(acc[t][0])), cmln2, -cmln2);
    float h1 = fmaf(flog2(1.f+fexp2(acc[t][1])), cmln2, -cmln2);
    float h2 = fmaf(flog2(1.f+fexp2(acc[t][2])), cmln2, -cmln2);
    float h3 = fmaf(flog2(1.f+fexp2(acc[t][3])), cmln2, -cmln2);
    u32x2 d; d[0]=pk2(h0,h1); d[1]=pk2(h2,h3);
    *(u32x2*)(&H[l15][t*16 + q*4]) = d;
  }
  // H bias block cols 128..159: col 128 = cm, rest 0
  {
    u32x2 zb; zb[0] = (q==0) ? pk2(cm_l, 0.f) : 0u; zb[1] = 0u;
    *(u32x2*)(&H[l15][128 + q*4]) = zb;
    u32x2 zz; zz[0] = 0u; zz[1] = 0u;
    *(u32x2*)(&H[l15][144 + q*4]) = zz;
  }

  // S2: (cm·H | cm) @ (fw2 | fb2)   — 5 k-tiles, same-wave DS ordering
  #pragma unroll
  for(int t=0;t<8;t++) acc[t] = (f32x4){0.f,0.f,0.f,0.f};
  #pragma unroll
  for(int kk=0;kk<5;kk++){
    bf16x8 a2 = *(const bf16x8*)(&H[l15][kk*32 + q*8]);
    #pragma unroll
    for(int t=0;t<8;t++){
      bf16x8 wv = *(const bf16x8*)(fw2f + ((kk*8+t)*64 + lane)*8);
      acc[t] = mfma16(a2, wv, acc[t]);
    }
  }
  // epilogue: pure agg += W * y  (bias & cutoff already inside acc)
  float aggp[8];
  #pragma unroll
  for(int t=0;t<8;t++){
    float s = acc[t][0]*yv0[t];
    s = fmaf(acc[t][1], yv1[t], s);
    s = fmaf(acc[t][2], yv2[t], s);
    aggp[t] = fmaf(acc[t][3], yv3[t], s);
  }
  // intra-wave q-reduce, then cross-wave reduce via LDS
  #pragma unroll
  for(int t=0;t<8;t++){
    float v = aggp[t];
    v += __shfl_xor(v, 16, 64);
    v += __shfl_xor(v, 32, 64);
    aggp[t] = v;
  }
  if(q==0){
    #pragma unroll
    for(int t=0;t<8;t++) Red[mt][t*16 + l15] = aggp[t];
  }
  __syncthreads();
  if(tid < 128){
    float s = Red[0][tid] + Red[1][tid] + Red[2][tid] + Red[3][tid];
    AGG[(size_t)atom*128 + tid] = s;
  }
}

// ---------------------------------------------------------------------------
// v = ssp(agg @ f2out + b) @ dense + b;  x += v;  (if !last) y = x @ in2f_next
__global__ __launch_bounds__(64) void k_out(const float* __restrict__ AGG,
                                            float* __restrict__ X,
                                            float* __restrict__ Y,
                                            const u16* __restrict__ f2of,
                                            const u16* __restrict__ denf,
                                            const u16* __restrict__ in2fN,
                                            const void* __restrict__ f2ob,
                                            const void* __restrict__ denb,
                                            const void* __restrict__ nmask,
                                            void* __restrict__ OUT,
                                            int last, int iidx){
  __shared__ __align__(16) u16 T[16][136];
  __shared__ __align__(16) u16 Xw[16][136];
  int isbf = probe_bf(nmask);
  int lane = threadIdx.x;
  int q = lane>>4, l15 = lane&15;
  int row0 = blockIdx.x*16;

  // G1': T^T = f2o^T @ agg^T, then ssp(+bias)
  f32x4 acc[8];
  #pragma unroll
  for(int t=0;t<8;t++) acc[t] = (f32x4){0.f,0.f,0.f,0.f};
  #pragma unroll
  for(int kk=0;kk<4;kk++){
    bf16x8 gf = ldfragA_f32(AGG + (size_t)(row0+l15)*128 + kk*32 + q*8);
    #pragma unroll
    for(int t=0;t<8;t++){
      bf16x8 wv = *(const bf16x8*)(f2of + ((kk*8+t)*64 + lane)*8);
      acc[t] = mfma16(wv, gf, acc[t]);       // D[col t*16+q*4+r][row l15]
    }
  }
  #pragma unroll
  for(int t=0;t<8;t++){
    f32x4 bv = ldin4(f2ob, (size_t)iidx*128 + t*16 + q*4, isbf);
    u32x2 d;
    d[0] = pk2(sspf(acc[t][0]+bv[0]), sspf(acc[t][1]+bv[1]));
    d[1] = pk2(sspf(acc[t][2]+bv[2]), sspf(acc[t][3]+bv[3]));
    *(u32x2*)(&T[l15][t*16 + q*4]) = d;
  }

  // G2': dense^T @ T^T + bias + X (residual)   (same-wave DS ordering)
  #pragma unroll
  for(int t=0;t<8;t++) acc[t] = (f32x4){0.f,0.f,0.f,0.f};
  #pragma unroll
  for(int kk=0;kk<4;kk++){
    bf16x8 tf = *(const bf16x8*)(&T[l15][kk*32 + q*8]);
    #pragma unroll
    for(int t=0;t<8;t++){
      bf16x8 wv = *(const bf16x8*)(denf + ((kk*8+t)*64 + lane)*8);
      acc[t] = mfma16(wv, tf, acc[t]);
    }
  }
  #pragma unroll
  for(int t=0;t<8;t++){
    size_t idx = (size_t)(row0+l15)*128 + t*16 + q*4;
    f32x4 bv = ldin4(denb, (size_t)iidx*128 + t*16 + q*4, isbf);
    f32x4 xv = *(const f32x4*)(X + idx);
    f32x4 xn;
    #pragma unroll
    for(int r=0;r<4;r++) xn[r] = xv[r] + acc[t][r] + bv[r];
    *(f32x4*)(X + idx) = xn;
    if(last){
      if(isbf){
        u32x2 o; o[0]=pk2(xn[0],xn[1]); o[1]=pk2(xn[2],xn[3]);
        *(u32x2*)((u16*)OUT + idx) = o;
      } else {
        *(f32x4*)((float*)OUT + idx) = xn;
      }
    } else {
      u32x2 d; d[0]=pk2(xn[0],xn[1]); d[1]=pk2(xn[2],xn[3]);
      *(u32x2*)(&Xw[l15][t*16 + q*4]) = d;
    }
  }
  if(!last){
    // G3': y^T = in2f^T @ xnew^T  -> float4 Y stores
    #pragma unroll
    for(int t=0;t<8;t++) acc[t] = (f32x4){0.f,0.f,0.f,0.f};
    #pragma unroll
    for(int kk=0;kk<4;kk++){
      bf16x8 xf = *(const bf16x8*)(&Xw[l15][kk*32 + q*8]);
      #pragma unroll
      for(int t=0;t<8;t++){
        bf16x8 wv = *(const bf16x8*)(in2fN + ((kk*8+t)*64 + lane)*8);
        acc[t] = mfma16(wv, xf, acc[t]);
      }
    }
    #pragma unroll
    for(int t=0;t<8;t++)
      *(f32x4*)(Y + (size_t)(row0+l15)*128 + t*16 + q*4) = acc[t];
  }
}

// ---------------------------------------------------------------------------
extern "C" void kernel_launch(void* const* d_in, const int* in_sizes, int n_in,
                              void* d_out, int out_size, void* d_ws, size_t ws_size,
                              hipStream_t stream){
  const void* pos   = d_in[0];
  const void* cell  = d_in[1];
  const void* cello = d_in[2];
  const void* nmask = d_in[3];
  // d_in[4] atom_mask: unused by the output
  const void* emb   = d_in[5];
  const void* fw1   = d_in[6];
  const void* fb1   = d_in[7];
  const void* fw2   = d_in[8];
  const void* fb2   = d_in[9];
  const void* in2f  = d_in[10];
  const void* f2o   = d_in[11];
  const void* f2ob  = d_in[12];
  const void* den   = d_in[13];
  const void* denb  = d_in[14];
  const int* z      = (const int*)d_in[15];
  const int* nbrs   = (const int*)d_in[16];

  char* ws = (char*)d_ws;
  float* X   = (float*)(ws);                 //  4 MB fp32 features
  float* Y   = (float*)(ws +  4194304);      //  4 MB projected features
  float* AGG = (float*)(ws +  8388608);      //  4 MB cfconv aggregate
  float* R   = (float*)(ws + 12582912);      //  2 MB distances
  float* CMp = (float*)(ws + 14680064);      //  2 MB cutoff*mask
  u16*   WF  = (u16*)  (ws + 16777216);      // 432 KB weight B-frags

  k_setup<<<6252, 256, 0, stream>>>(pos, cell, cello, nmask, emb,
                                    fw1, fb1, fw2, fb2, in2f, f2o, den,
                                    z, nbrs, X, R, CMp, WF);
  k_proj <<< 512,  64, 0, stream>>>(X, WF + WF_IN2F, Y);

  for(int i=0;i<3;i++){
    const u16* base = WF + (size_t)i*WF_STRIDE;
    k_cfconv<<<8192, 256, 0, stream>>>(R, CMp, Y, nbrs,
                                       base + 0       /* fw1 frags (log2e, fb1 row) */,
                                       base + WF_FW2  /* fw2 frags (+fb2 row) */,
                                       AGG);
    const u16* in2fN = (i<2) ? (WF + (size_t)(i+1)*WF_STRIDE + WF_IN2F) : WF;
    k_out<<<512, 64, 0, stream>>>(AGG, X, Y,
                                  base + WF_F2O  /* f2out frags */,
                                  base + WF_DEN  /* dense frags */,
                                  in2fN,
                                  f2ob, denb, nmask,
                                  d_out, (i==2) ? 1 : 0, i);
  }
}

// Round 9
// 217.086 us; speedup vs baseline: 1.5229x; 1.5229x over previous
//
#include <hip/hip_runtime.h>

typedef __attribute__((ext_vector_type(8))) short bf16x8;
typedef __attribute__((ext_vector_type(4))) float f32x4;
typedef __attribute__((ext_vector_type(2))) unsigned int u32x2;
typedef __attribute__((ext_vector_type(4))) unsigned int u32x4;
typedef __attribute__((ext_vector_type(2))) __bf16 bf16x2t;
typedef unsigned short u16;
typedef unsigned int u32;

#define DI __device__ __forceinline__

// Problem constants: B=8, A=1024, NB=64, NAB=NF=128, NG=25, NI=3
#define NKNOT 2048

DI float b2f(u16 u){ union{u32 i; float f;} v; v.i = ((u32)u)<<16; return v.f; }
DI float asf(u32 u){ union{u32 i; float f;} v; v.i = u; return v.f; }
DI u16 f2b(float f){ union{float f; u32 i;} v; v.f=f; u32 u=v.i;
                     return (u16)((u + 0x7fffu + ((u>>16)&1u))>>16); }
DI u32 pk2(float lo, float hi){
#if __has_builtin(__builtin_amdgcn_cvt_pk_bf16_f32)
  bf16x2t h = __builtin_amdgcn_cvt_pk_bf16_f32(lo, hi);
  u32 d; __builtin_memcpy(&d, &h, 4); return d;
#else
  return (u32)f2b(lo) | ((u32)f2b(hi)<<16);
#endif
}
DI float fexp2(float x){
#if __has_builtin(__builtin_amdgcn_exp2f)
  return __builtin_amdgcn_exp2f(x);
#else
  return __expf(x*0.6931471805599453f);
#endif
}
DI float flog2(float x){
#if __has_builtin(__builtin_amdgcn_logf)
  return __builtin_amdgcn_logf(x);
#else
  return __logf(x)*1.4426950408889634f;
#endif
}
DI float ldin(const void* p, size_t i, int isbf){
  return isbf ? b2f(((const u16*)p)[i]) : ((const float*)p)[i];
}
DI f32x4 ldin4(const void* p, size_t i, int isbf){
  if(isbf){
    u32x2 d = *(const u32x2*)((const u16*)p + i);
    f32x4 r;
    r[0] = b2f((u16)(d[0]&0xffff)); r[1] = b2f((u16)(d[0]>>16));
    r[2] = b2f((u16)(d[1]&0xffff)); r[3] = b2f((u16)(d[1]>>16));
    return r;
  }
  return *(const f32x4*)((const float*)p + i);
}
DI int probe_bf(const void* nmask){ return ((const u16*)nmask)[0] == 0x3F80u; }

DI f32x4 mfma16(bf16x8 a, bf16x8 b, f32x4 c){
  return __builtin_amdgcn_mfma_f32_16x16x32_bf16(a,b,c,0,0,0);
}
DI bf16x8 ldfragA_f32(const float* p){
  f32x4 a = ((const f32x4*)p)[0], b = ((const f32x4*)p)[1];
  union{ u32 d[4]; bf16x8 v; } u;
  u.d[0]=pk2(a[0],a[1]); u.d[1]=pk2(a[2],a[3]);
  u.d[2]=pk2(b[0],b[1]); u.d[3]=pk2(b[2],b[3]);
  return u.v;
}
DI float sspf(float x){ return __logf(1.f + __expf(x)) - 0.6931471805599453f; }

// WF layout per interaction (u16 offsets; frag = 512 u16):
//   fw1   frags 0..7     off 0      (K=32: rows 0..24 = fw1*log2e, 25 = fb1*log2e)
//   fw2   frags 8..47    off 4096   (kk 0..4; kk=4 row k=128 = fb2)
//   in2f  frags 48..79   off 24576
//   f2o   frags 80..111  off 40960
//   dense frags 112..143 off 57344
#define WF_STRIDE 73728
#define WF_FW2    4096
#define WF_IN2F   24576
#define WF_F2O    40960
#define WF_DEN    57344

// ---------------------------------------------------------------------------
// Fused setup: blocks [0,4096) embed | [4096,6144) dist->desc | [6144,6252) wfrag
// desc per pair (8 B): {f16 a0, f16 a1} | {u16 knot, u16 nbr}
//   a0 = cm*(1-frac), a1 = cm*frac; cm=0 for masked/out-of-cutoff pairs.
__global__ __launch_bounds__(256) void k_setup(const void* __restrict__ pos,
                                               const void* __restrict__ cell,
                                               const void* __restrict__ cello,
                                               const void* __restrict__ nmask,
                                               const void* __restrict__ emb,
                                               const void* __restrict__ fw1,
                                               const void* __restrict__ fb1,
                                               const void* __restrict__ fw2,
                                               const void* __restrict__ fb2,
                                               const void* __restrict__ in2f,
                                               const void* __restrict__ f2o,
                                               const void* __restrict__ den,
                                               const int* __restrict__ z,
                                               const int* __restrict__ nbrs,
                                               float* __restrict__ X,
                                               u32x2* __restrict__ DESC,
                                               u16* __restrict__ WF){
  int isbf = probe_bf(nmask);
  int bx = blockIdx.x, tid = threadIdx.x;
  if(bx < 4096){
    int idx = bx*256 + tid;                    // < 8192*128
    int a = idx>>7, f = idx&127;
    X[idx] = ldin(emb, (size_t)z[a]*128 + f, isbf);
    return;
  }
  if(bx < 6144){
    int pairIdx = (bx-4096)*256 + tid;         // < 8192*64
    int atom = pairIdx>>6;
    int b = atom>>10;
    int nb = nbrs[pairIdx];
    int jrow = (b<<10) + nb;
    float pi0=ldin(pos,atom*3+0,isbf), pi1=ldin(pos,atom*3+1,isbf), pi2=ldin(pos,atom*3+2,isbf);
    float pj0=ldin(pos,jrow*3+0,isbf), pj1=ldin(pos,jrow*3+1,isbf), pj2=ldin(pos,jrow*3+2,isbf);
    float co0=ldin(cello,(size_t)pairIdx*3+0,isbf),
          co1=ldin(cello,(size_t)pairIdx*3+1,isbf),
          co2=ldin(cello,(size_t)pairIdx*3+2,isbf);
    size_t cb = (size_t)b*9;
    pj0 += co0*ldin(cell,cb+0,isbf) + co1*ldin(cell,cb+3,isbf) + co2*ldin(cell,cb+6,isbf);
    pj1 += co0*ldin(cell,cb+1,isbf) + co1*ldin(cell,cb+4,isbf) + co2*ldin(cell,cb+7,isbf);
    pj2 += co0*ldin(cell,cb+2,isbf) + co1*ldin(cell,cb+5,isbf) + co2*ldin(cell,cb+8,isbf);
    float d0 = pj0-pi0, d1 = pj1-pi1, d2 = pj2-pi2;
    float dd = d0*d0 + d1*d1 + d2*d2;
    float m  = ldin(nmask,pairIdx,isbf);
    float r  = sqrtf(m>0.f ? dd : 1.f) * m;
    float c  = 0.5f*(__cosf(r*3.14159265358979f/5.f)+1.f) * ((r<5.f)?1.f:0.f) * m;
    float s  = r * ((float)(NKNOT-1)/5.0f);
    int   k  = (int)s; if(k > NKNOT-2) k = NKNOT-2;
    float fr = s - (float)k;
    float a0 = c*(1.f-fr), a1 = c*fr;
    union{ _Float16 h[2]; u32 u; } pa;
    pa.h[0] = (_Float16)a0; pa.h[1] = (_Float16)a1;
    u32x2 dsc; dsc[0] = pa.u; dsc[1] = (u32)k | ((u32)nb<<16);
    DESC[pairIdx] = dsc;
    return;
  }
  // weight fragments: wid in [0,432) = 3 interactions x 144 frags
  int wid = (bx-6144)*4 + (tid>>6);
  int lane = tid & 63;
  int q = lane>>4, l15 = lane&15;
  int i = wid/144, r = wid%144;
  int mat, kk, t;
  if(r < 8){ mat=0; kk=0; t=r; }
  else if(r < 48){ int r2 = r-8; mat=1; kk=r2>>3; t=r2&7; }
  else { int r3 = r-48; mat = 2 + (r3>>5); kk = (r3>>3)&3; t = r3&7; }
  const void* src; size_t sbase; int K; int off;
  switch(mat){
    case 0:  src = fw1;  sbase=(size_t)i*3200;  K=25;  off=0;       break;
    case 1:  src = fw2;  sbase=(size_t)i*16384; K=128; off=WF_FW2;  break;
    case 2:  src = in2f; sbase=(size_t)i*16384; K=128; off=WF_IN2F; break;
    case 3:  src = f2o;  sbase=(size_t)i*16384; K=128; off=WF_F2O;  break;
    default: src = den;  sbase=(size_t)i*16384; K=128; off=WF_DEN;  break;
  }
  int c = t*16 + l15;
  bf16x8 frag;
  #pragma unroll
  for(int j=0;j<8;j++){
    int k = kk*32 + q*8 + j;
    float v;
    if(k < K)                 v = ldin(src, sbase + (size_t)k*128 + c, isbf);
    else if(mat==0 && k==25)  v = ldin(fb1, (size_t)i*128 + c, isbf);   // fb1 row
    else if(mat==1 && k==128) v = ldin(fb2, (size_t)i*128 + c, isbf);   // fb2 row
    else                      v = 0.f;
    if(mat==0) v *= 1.4426950408889634f;       // log2e pre-scale (exp2 domain)
    frag[j] = (short)f2b(v);
  }
  *(bf16x8*)(WF + (size_t)i*WF_STRIDE + off + ((kk*8+t)*64 + lane)*8) = frag;
}

// ---------------------------------------------------------------------------
// Filter table: T[i][knot][128] bf16 = ssp(f(r_k)@fw1+fb1)@fw2 + fb2 (exact MLP
// at knots, via MFMA).  One wave per 16 knots; 384 waves total.
__global__ __launch_bounds__(256) void k_table(const u16* __restrict__ WF,
                                               u16* __restrict__ T){
  __shared__ __align__(16) u16 Hb[4][16][168];
  int tid = threadIdx.x;
  int widx = tid>>6;
  int lane = tid & 63;
  int q = lane>>4, l15 = lane&15;
  int wid = blockIdx.x*4 + widx;    // 0..383
  int i  = wid>>7;
  int kb = (wid&127)*16;
  const u16* fw1f = WF + (size_t)i*WF_STRIDE;
  const u16* fw2f = WF + (size_t)i*WF_STRIDE + WF_FW2;
  u16 (*H)[168] = Hb[widx];

  const float width = 5.0f/24.0f;
  const float c2 = (-0.5f/(width*width))*1.4426950408889634f;
  float r = (float)(kb + l15) * (5.0f/(float)(NKNOT-1));

  float gv[8];
  #pragma unroll
  for(int j=0;j<8;j++){
    int k = q*8+j;
    if(k < 25){ float t = fmaf(-width,(float)k,r); gv[j] = fexp2(c2*t*t); }
    else gv[j] = (k==25) ? 1.f : 0.f;
  }
  union{ u32 d[4]; bf16x8 v; } afu;
  afu.d[0]=pk2(gv[0],gv[1]); afu.d[1]=pk2(gv[2],gv[3]);
  afu.d[2]=pk2(gv[4],gv[5]); afu.d[3]=pk2(gv[6],gv[7]);
  bf16x8 af = afu.v;

  f32x4 acc[8];
  #pragma unroll
  for(int t=0;t<8;t++){
    bf16x8 w1 = *(const bf16x8*)(fw1f + (size_t)t*512 + lane*8);
    acc[t] = mfma16(w1, af, (f32x4){0.f,0.f,0.f,0.f});
  }
  const float ln2 = 0.69314718055994531f;
  #pragma unroll
  for(int t=0;t<8;t++){
    float h0 = fmaf(flog2(1.f+fexp2(acc[t][0])), ln2, -ln2);
    float h1 = fmaf(flog2(1.f+fexp2(acc[t][1])), ln2, -ln2);
    float h2 = fmaf(flog2(1.f+fexp2(acc[t][2])), ln2, -ln2);
    float h3 = fmaf(flog2(1.f+fexp2(acc[t][3])), ln2, -ln2);
    u32x2 d; d[0]=pk2(h0,h1); d[1]=pk2(h2,h3);
    *(u32x2*)(&H[l15][t*16 + q*4]) = d;
  }
  { // bias block cols 128..159: col128 = 1.0 (adds fb2), rest 0
    u32x2 zb; zb[0] = (q==0) ? pk2(1.f, 0.f) : 0u; zb[1] = 0u;
    *(u32x2*)(&H[l15][128 + q*4]) = zb;
    u32x2 zz; zz[0]=0u; zz[1]=0u;
    *(u32x2*)(&H[l15][144 + q*4]) = zz;
  }
  #pragma unroll
  for(int t=0;t<8;t++) acc[t] = (f32x4){0.f,0.f,0.f,0.f};
  #pragma unroll
  for(int kk=0;kk<5;kk++){
    bf16x8 a2 = *(const bf16x8*)(&H[l15][kk*32 + q*8]);
    #pragma unroll
    for(int t=0;t<8;t++){
      bf16x8 wv = *(const bf16x8*)(fw2f + ((kk*8+t)*64 + lane)*8);
      acc[t] = mfma16(a2, wv, acc[t]);
    }
  }
  // store T[i][kb+l15][col] (bf16, pk2 pairs)
  u16* dst = T + ((size_t)(i*NKNOT + kb + l15))*128;
  #pragma unroll
  for(int t=0;t<8;t++){
    u32x2 d; d[0]=pk2(acc[t][0],acc[t][1]); d[1]=pk2(acc[t][2],acc[t][3]);
    *(u32x2*)(dst + t*16 + q*4) = d;
  }
}

// ---------------------------------------------------------------------------
// y = x @ in2f (iteration 0).
__global__ __launch_bounds__(64) void k_proj(const float* __restrict__ X,
                                             const u16* __restrict__ wf,
                                             float* __restrict__ Y){
  int wid = blockIdx.x;
  int lane = threadIdx.x;
  int q = lane>>4, l15 = lane&15;
  int row0 = wid*16;
  f32x4 acc[8];
  #pragma unroll
  for(int t=0;t<8;t++) acc[t] = (f32x4){0.f,0.f,0.f,0.f};
  #pragma unroll
  for(int kk=0;kk<4;kk++){
    bf16x8 xf = ldfragA_f32(X + (size_t)(row0+l15)*128 + kk*32 + q*8);
    #pragma unroll
    for(int t=0;t<8;t++){
      bf16x8 wv = *(const bf16x8*)(wf + ((kk*8+t)*64 + lane)*8);
      acc[t] = mfma16(wv, xf, acc[t]);
    }
  }
  #pragma unroll
  for(int t=0;t<8;t++)
    *(f32x4*)(Y + (size_t)(row0+l15)*128 + t*16 + q*4) = acc[t];
}

// ---------------------------------------------------------------------------
// CFConv via table lerp: one wave per atom, lane owns filters 2*lane, 2*lane+1.
// Per neighbor: W = a0*T[k] + a1*T[k+1]  (a0,a1 carry cutoff*mask & lerp frac);
// agg += W * y[nbr].  No MFMA, no LDS, no transcendentals, no barriers.
__global__ __launch_bounds__(256) void k_cfconv(const u32x2* __restrict__ desc,
                                                const u16* __restrict__ T,
                                                const float* __restrict__ Y,
                                                float* __restrict__ AGG){
  int tid = threadIdx.x;
  int atom = __builtin_amdgcn_readfirstlane(blockIdx.x*4 + (tid>>6));
  int lane = tid & 63;
  const u32x2* dp = desc + (size_t)atom*64;
  const float* Yb = Y + (size_t)(atom & ~1023)*128;
  float ax = 0.f, ay = 0.f;
  #pragma unroll 4
  for(int p=0;p<64;p++){
    u32x2 d = dp[p];
    union{ u32 u; _Float16 h[2]; } pa; pa.u = d[0];
    float a0 = (float)pa.h[0], a1 = (float)pa.h[1];
    u32 krow = d[1] & 0xffffu;
    u32 nbr  = d[1] >> 16;
    const u16* tr = T + (size_t)krow*128;
    u32 t0 = *(const u32*)(tr + lane*2);          // filters 2l,2l+1 @ knot k
    u32 t1 = *(const u32*)(tr + 128 + lane*2);    // @ knot k+1
    float2 yv = *(const float2*)(Yb + (size_t)nbr*128 + lane*2);
    float t0lo = asf(t0<<16), t0hi = asf(t0 & 0xffff0000u);
    float t1lo = asf(t1<<16), t1hi = asf(t1 & 0xffff0000u);
    float wlo = fmaf(a1, t1lo, a0*t0lo);
    float whi = fmaf(a1, t1hi, a0*t0hi);
    ax = fmaf(wlo, yv.x, ax);
    ay = fmaf(whi, yv.y, ay);
  }
  float2 o; o.x = ax; o.y = ay;
  *(float2*)(AGG + (size_t)atom*128 + lane*2) = o;
}

// ---------------------------------------------------------------------------
// v = ssp(agg @ f2out + b) @ dense + b;  x += v;  (if !last) y = x @ in2f_next
// 4 waves per 16-row tile (t-split) with barriers: ~3x shorter serial chain.
__global__ __launch_bounds__(256) void k_out(const float* __restrict__ AGG,
                                             float* __restrict__ X,
                                             float* __restrict__ Y,
                                             const u16* __restrict__ f2of,
                                             const u16* __restrict__ denf,
                                             const u16* __restrict__ in2fN,
                                             const void* __restrict__ f2ob,
                                             const void* __restrict__ denb,
                                             const void* __restrict__ nmask,
                                             void* __restrict__ OUT,
                                             int last, int iidx){
  __shared__ __align__(16) u16 T[16][136];
  __shared__ __align__(16) u16 Xw[16][136];
  int isbf = probe_bf(nmask);
  int widx = threadIdx.x>>6;        // wave owns t = widx*2, widx*2+1
  int lane = threadIdx.x & 63;
  int q = lane>>4, l15 = lane&15;
  int row0 = blockIdx.x*16;

  // G1': ssp(f2o^T @ agg^T + bias) -> T slices
  f32x4 acc[2];
  #pragma unroll
  for(int tt=0;tt<2;tt++) acc[tt] = (f32x4){0.f,0.f,0.f,0.f};
  #pragma unroll
  for(int kk=0;kk<4;kk++){
    bf16x8 gf = ldfragA_f32(AGG + (size_t)(row0+l15)*128 + kk*32 + q*8);
    #pragma unroll
    for(int tt=0;tt<2;tt++){
      int t = widx*2+tt;
      bf16x8 wv = *(const bf16x8*)(f2of + ((kk*8+t)*64 + lane)*8);
      acc[tt] = mfma16(wv, gf, acc[tt]);
    }
  }
  #pragma unroll
  for(int tt=0;tt<2;tt++){
    int t = widx*2+tt;
    f32x4 bv = ldin4(f2ob, (size_t)iidx*128 + t*16 + q*4, isbf);
    u32x2 d;
    d[0] = pk2(sspf(acc[tt][0]+bv[0]), sspf(acc[tt][1]+bv[1]));
    d[1] = pk2(sspf(acc[tt][2]+bv[2]), sspf(acc[tt][3]+bv[3]));
    *(u32x2*)(&T[l15][t*16 + q*4]) = d;
  }
  __syncthreads();

  // G2': dense^T @ T^T + bias + X (residual)
  #pragma unroll
  for(int tt=0;tt<2;tt++) acc[tt] = (f32x4){0.f,0.f,0.f,0.f};
  #pragma unroll
  for(int kk=0;kk<4;kk++){
    bf16x8 tf = *(const bf16x8*)(&T[l15][kk*32 + q*8]);
    #pragma unroll
    for(int tt=0;tt<2;tt++){
      int t = widx*2+tt;
      bf16x8 wv = *(const bf16x8*)(denf + ((kk*8+t)*64 + lane)*8);
      acc[tt] = mfma16(wv, tf, acc[tt]);
    }
  }
  #pragma unroll
  for(int tt=0;tt<2;tt++){
    int t = widx*2+tt;
    size_t idx = (size_t)(row0+l15)*128 + t*16 + q*4;
    f32x4 bv = ldin4(denb, (size_t)iidx*128 + t*16 + q*4, isbf);
    f32x4 xv = *(const f32x4*)(X + idx);
    f32x4 xn;
    #pragma unroll
    for(int r=0;r<4;r++) xn[r] = xv[r] + acc[tt][r] + bv[r];
    *(f32x4*)(X + idx) = xn;
    if(last){
      if(isbf){
        u32x2 o; o[0]=pk2(xn[0],xn[1]); o[1]=pk2(xn[2],xn[3]);
        *(u32x2*)((u16*)OUT + idx) = o;
      } else {
        *(f32x4*)((float*)OUT + idx) = xn;
      }
    } else {
      u32x2 d; d[0]=pk2(xn[0],xn[1]); d[1]=pk2(xn[2],xn[3]);
      *(u32x2*)(&Xw[l15][t*16 + q*4]) = d;
    }
  }
  if(!last){
    __syncthreads();
    // G3': y^T = in2f^T @ xnew^T
    #pragma unroll
    for(int tt=0;tt<2;tt++) acc[tt] = (f32x4){0.f,0.f,0.f,0.f};
    #pragma unroll
    for(int kk=0;kk<4;kk++){
      bf16x8 xf = *(const bf16x8*)(&Xw[l15][kk*32 + q*8]);
      #pragma unroll
      for(int tt=0;tt<2;tt++){
        int t = widx*2+tt;
        bf16x8 wv = *(const bf16x8*)(in2fN + ((kk*8+t)*64 + lane)*8);
        acc[tt] = mfma16(wv, xf, acc[tt]);
      }
    }
    #pragma unroll
    for(int tt=0;tt<2;tt++){
      int t = widx*2+tt;
      *(f32x4*)(Y + (size_t)(row0+l15)*128 + t*16 + q*4) = acc[tt];
    }
  }
}

// ---------------------------------------------------------------------------
extern "C" void kernel_launch(void* const* d_in, const int* in_sizes, int n_in,
                              void* d_out, int out_size, void* d_ws, size_t ws_size,
                              hipStream_t stream){
  const void* pos   = d_in[0];
  const void* cell  = d_in[1];
  const void* cello = d_in[2];
  const void* nmask = d_in[3];
  // d_in[4] atom_mask: unused by the output
  const void* emb   = d_in[5];
  const void* fw1   = d_in[6];
  const void* fb1   = d_in[7];
  const void* fw2   = d_in[8];
  const void* fb2   = d_in[9];
  const void* in2f  = d_in[10];
  const void* f2o   = d_in[11];
  const void* f2ob  = d_in[12];
  const void* den   = d_in[13];
  const void* denb  = d_in[14];
  const int* z      = (const int*)d_in[15];
  const int* nbrs   = (const int*)d_in[16];

  char* ws = (char*)d_ws;
  float* X    = (float*)(ws);                 //  4 MB fp32 features
  float* Y    = (float*)(ws +  4194304);      //  4 MB projected features
  float* AGG  = (float*)(ws +  8388608);      //  4 MB cfconv aggregate
  u32x2* DESC = (u32x2*)(ws + 12582912);      //  4 MB pair descriptors
  u16*   WF   = (u16*)  (ws + 16777216);      // 432 KB weight B-frags
  u16*   Tt   = (u16*)  (ws + 17301504);      //  1.5 MB filter tables (bf16)

  k_setup<<<6252, 256, 0, stream>>>(pos, cell, cello, nmask, emb,
                                    fw1, fb1, fw2, fb2, in2f, f2o, den,
                                    z, nbrs, X, DESC, WF);
  k_table<<<  96, 256, 0, stream>>>(WF, Tt);
  k_proj <<< 512,  64, 0, stream>>>(X, WF + WF_IN2F, Y);

  for(int i=0;i<3;i++){
    const u16* base = WF + (size_t)i*WF_STRIDE;
    k_cfconv<<<2048, 256, 0, stream>>>(DESC, Tt + (size_t)i*NKNOT*128, Y, AGG);
    const u16* in2fN = (i<2) ? (WF + (size_t)(i+1)*WF_STRIDE + WF_IN2F) : WF;
    k_out<<<512, 256, 0, stream>>>(AGG, X, Y,
                                   base + WF_F2O, base + WF_DEN,
                                   in2fN,
                                   f2ob, denb, nmask,
                                   d_out, (i==2) ? 1 : 0, i);
  }
}